// Round 3
// baseline (165.982 us; speedup 1.0000x reference)
//
#include <hip/hip_runtime.h>
#include <math.h>

#define Bn   64
#define Nn   512
#define Dn   256
#define IMGn 51

typedef __attribute__((ext_vector_type(8))) short bf16x8;
typedef __attribute__((ext_vector_type(4))) float f32x4;
typedef __attribute__((ext_vector_type(4))) unsigned short u16x4;

__device__ inline unsigned short f2b(float f) {            // fp32 -> bf16 RNE
    union { float f; unsigned u; } v; v.f = f;
    unsigned r = v.u + 0x7fffu + ((v.u >> 16) & 1u);
    return (unsigned short)(r >> 16);
}

// ---------------- fp32 -> bf16 bulk convert (float4 / thread-iter) -------------
__global__ __launch_bounds__(256) void k_cvt(const float* __restrict__ in,
                                             unsigned short* __restrict__ out, int n4) {
    int stride = gridDim.x * 256;
    for (int i = blockIdx.x * 256 + threadIdx.x; i < n4; i += stride) {
        float4 v = ((const float4*)in)[i];
        u16x4 o = { f2b(v.x), f2b(v.y), f2b(v.z), f2b(v.w) };
        ((u16x4*)out)[i] = o;
    }
}

// three 256x256 weights in one launch (grid.y selects the pair)
__global__ __launch_bounds__(256) void k_cvtw(const float* __restrict__ w0,
                                              const float* __restrict__ w1,
                                              const float* __restrict__ wf,
                                              unsigned short* __restrict__ o0,
                                              unsigned short* __restrict__ o1,
                                              unsigned short* __restrict__ of) {
    const float* src = (blockIdx.y == 0) ? w0 : (blockIdx.y == 1) ? w1 : wf;
    unsigned short* dst = (blockIdx.y == 0) ? o0 : (blockIdx.y == 1) ? o1 : of;
    int i = blockIdx.x * 256 + threadIdx.x;                  // 64 blocks x 256 = 16384 float4
    float4 v = ((const float4*)src)[i];
    u16x4 o = { f2b(v.x), f2b(v.y), f2b(v.z), f2b(v.w) };
    ((u16x4*)dst)[i] = o;
}

// ---------------- row L2-normalize fp32 -> bf16, one wave per row --------------
__global__ __launch_bounds__(256) void k_norm(const float* __restrict__ in,
                                              unsigned short* __restrict__ out) {
    int idx  = blockIdx.x * 256 + threadIdx.x;
    int row  = idx >> 6;
    int lane = threadIdx.x & 63;
    float4 v = ((const float4*)(in + (size_t)row * Dn))[lane];
    float ss = v.x * v.x + v.y * v.y + v.z * v.z + v.w * v.w;
#pragma unroll
    for (int m = 1; m < 64; m <<= 1) ss += __shfl_xor(ss, m);
    float inv = 1.0f / fmaxf(sqrtf(ss), 1e-8f);
    u16x4 o = { f2b(v.x * inv), f2b(v.y * inv), f2b(v.z * inv), f2b(v.w * inv) };
    ((u16x4*)(out + (size_t)row * Dn))[lane] = o;
}

// ---------------- MFMA GEMM core: C = A(128xK) * Bt(128xK)^T -------------------
// Tile 128x128, BK=32, 4 waves (2x2), each wave 64x64 = 4x4 frags of 16x16x32.
// LDS tiles [128 rows x 32 k] bf16, linear (row stride 64 B), staged by
// global_load_lds width 16 with source-side XOR swizzle: 16B slot s of row r
// holds global slot s ^ ((r>>1)&3)  -> frag ds_read_b128 is 2-way (free).

__device__ inline void stage128x32(const unsigned short* __restrict__ src, int ldk,
                                   char* ldsbase, int tid) {
    const int wave = tid >> 6, lane = tid & 63;
#pragma unroll
    for (int it = 0; it < 2; ++it) {
        const int chunk = wave * 128 + it * 64 + lane;   // 512 chunks of 16B
        const int row = chunk >> 2, s = chunk & 3;
        const char* g = (const char*)(src + (size_t)row * ldk) + ((s ^ ((row >> 1) & 3)) << 4);
        char* l = ldsbase + (size_t)(wave * 2048 + it * 1024);   // wave-uniform base
        __builtin_amdgcn_global_load_lds((const __attribute__((address_space(1))) void*)g,
                                         (__attribute__((address_space(3))) void*)l,
                                         16, 0, 0);
    }
}

__device__ inline bf16x8 frag(const char* ldsbase, int row, int s) {
    return *(const bf16x8*)(ldsbase + row * 64 + ((s ^ ((row >> 1) & 3)) << 4));
}

enum { EPI_GRAM = 0, EPI_TRANS = 1, EPI_BIASH = 2, EPI_FINAL = 3 };

template<int EPI>
__global__ __launch_bounds__(256) void k_mfma(const unsigned short* __restrict__ Abase,
                                              const unsigned short* __restrict__ Bbase,
                                              void* __restrict__ outp,
                                              const float* __restrict__ bias,
                                              const int* __restrict__ noun,
                                              int K, int lda, int ldb, long sA, long sB) {
    extern __shared__ char smem[];
    char* As = smem;
    char* Bs = smem + 8192;
    const int tid = threadIdx.x, lane = tid & 63, wave = tid >> 6;
    const int wr = wave >> 1, wc = wave & 1;
    const int r16 = lane & 15, s = lane >> 4;
    const size_t bz = blockIdx.z;
    const unsigned short* A  = Abase + bz * sA + (size_t)blockIdx.y * 128 * lda;
    const unsigned short* Bt = Bbase + bz * sB + (size_t)blockIdx.x * 128 * ldb;

    f32x4 acc[4][4];
#pragma unroll
    for (int m = 0; m < 4; ++m)
#pragma unroll
        for (int n = 0; n < 4; ++n)
            acc[m][n] = (f32x4){0.f, 0.f, 0.f, 0.f};

    for (int kt = 0; kt < K; kt += 32) {
        stage128x32(A + kt, lda, As, tid);
        stage128x32(Bt + kt, ldb, Bs, tid);
        __syncthreads();
        bf16x8 af[4], bv[4];
#pragma unroll
        for (int m = 0; m < 4; ++m) af[m] = frag(As, wr * 64 + m * 16 + r16, s);
#pragma unroll
        for (int n = 0; n < 4; ++n) bv[n] = frag(Bs, wc * 64 + n * 16 + r16, s);
#pragma unroll
        for (int m = 0; m < 4; ++m)
#pragma unroll
            for (int n = 0; n < 4; ++n)
                acc[m][n] = __builtin_amdgcn_mfma_f32_16x16x32_bf16(af[m], bv[n], acc[m][n], 0, 0, 0);
        __syncthreads();
    }

    const int row0 = blockIdx.y * 128, col0 = blockIdx.x * 128;
    unsigned short* lt = (unsigned short*)smem;              // [128][136] bounce

    if constexpr (EPI == EPI_GRAM) {
        const int* nm = noun + bz * Nn;
#pragma unroll
        for (int n = 0; n < 4; ++n) {
            const int cl = wc * 64 + n * 16 + r16;
            const int c  = col0 + cl;
            const float nmc = (c < IMGn) ? 0.f : (float)nm[c];
#pragma unroll
            for (int m = 0; m < 4; ++m)
#pragma unroll
                for (int i = 0; i < 4; ++i) {
                    const int rl = wr * 64 + m * 16 + s * 4 + i;
                    const int r  = row0 + rl;
                    float mask;
                    if (r < IMGn)      mask = nmc;
                    else if (c < IMGn) mask = (float)nm[r];
                    else               mask = 1.f;
                    lt[rl * 136 + cl] = f2b(acc[m][n][i] * mask);
                }
        }
        __syncthreads();
        unsigned short* out = (unsigned short*)outp + bz * ((size_t)Nn * Nn);
        const int row = tid >> 1, h = tid & 1;
        const bf16x8* srcv = (const bf16x8*)(lt + (size_t)row * 136 + h * 64);
        bf16x8* dstv = (bf16x8*)(out + (size_t)(row0 + row) * Nn + col0 + h * 64);
#pragma unroll
        for (int q = 0; q < 8; ++q) dstv[q] = srcv[q];
    } else if constexpr (EPI == EPI_BIASH) {
#pragma unroll
        for (int n = 0; n < 4; ++n) {
            const int cl = wc * 64 + n * 16 + r16;
            const float bvv = bias[col0 + cl];
#pragma unroll
            for (int m = 0; m < 4; ++m)
#pragma unroll
                for (int i = 0; i < 4; ++i) {
                    const int rl = wr * 64 + m * 16 + s * 4 + i;
                    lt[rl * 136 + cl] = f2b(fmaxf(acc[m][n][i] + bvv, 0.f));
                }
        }
        __syncthreads();
        unsigned short* out = (unsigned short*)outp + bz * ((size_t)Nn * Dn);
        const int row = tid >> 1, h = tid & 1;
        const bf16x8* srcv = (const bf16x8*)(lt + (size_t)row * 136 + h * 64);
        bf16x8* dstv = (bf16x8*)(out + (size_t)(row0 + row) * Dn + col0 + h * 64);
#pragma unroll
        for (int q = 0; q < 8; ++q) dstv[q] = srcv[q];
    } else if constexpr (EPI == EPI_FINAL) {
        float* out = (float*)outp;
#pragma unroll
        for (int n = 0; n < 4; ++n) {
            const int c = col0 + wc * 64 + n * 16 + r16;
            const float bvv = bias[c];
#pragma unroll
            for (int m = 0; m < 4; ++m)
#pragma unroll
                for (int i = 0; i < 4; ++i) {
                    const int r = row0 + wr * 64 + m * 16 + s * 4 + i;
                    out[(size_t)r * Dn + c] = fmaxf(acc[m][n][i] + bvv, 0.f);
                }
        }
    } else {  // EPI_TRANS: out Ut[b][c][r_local], via padded-LDS transpose bounce
#pragma unroll
        for (int n = 0; n < 4; ++n)
#pragma unroll
            for (int m = 0; m < 4; ++m)
#pragma unroll
                for (int i = 0; i < 4; ++i) {
                    const int ct = wc * 64 + n * 16 + r16;
                    const int rt = wr * 64 + m * 16 + s * 4 + i;
                    lt[ct * 136 + rt] = f2b(acc[m][n][i]);
                }
        __syncthreads();
        const int bm = blockIdx.y;
        const size_t bb = bm >> 2;
        const int rl0 = (bm & 3) * 128;
        unsigned short* out = (unsigned short*)outp + bb * ((size_t)Dn * Nn);
        const int ct = tid >> 1, h = tid & 1;
        const bf16x8* srcv = (const bf16x8*)(lt + (size_t)ct * 136 + h * 64);
        bf16x8* dstv = (bf16x8*)(out + (size_t)(col0 + ct) * Nn + rl0 + h * 64);
#pragma unroll
        for (int q = 0; q < 8; ++q) dstv[q] = srcv[q];
    }
}

extern "C" void kernel_launch(void* const* d_in, const int* in_sizes, int n_in,
                              void* d_out, int out_size, void* d_ws, size_t ws_size,
                              hipStream_t stream) {
    const float* input_1 = (const float*)d_in[0];
    const float* input_2 = (const float*)d_in[1];
    const int*   noun    = (const int*)d_in[3];
    const float* w0 = (const float*)d_in[4];
    const float* b0 = (const float*)d_in[5];
    const float* w1 = (const float*)d_in[6];
    const float* b1 = (const float*)d_in[7];
    const float* wf = (const float*)d_in[8];
    const float* bf = (const float*)d_in[9];

    unsigned short* ws  = (unsigned short*)d_ws;
    unsigned short* T   = ws;                    // 64*512*256
    unsigned short* A0  = ws + 8388608;          // input_1 bf16
    unsigned short* adj = ws + 16777216;         // 64*512*512
    unsigned short* Ut  = ws + 33554432;         // 64*256*512
    unsigned short* H1  = ws + 41943040;
    unsigned short* H2  = ws + 50331648;
    unsigned short* w0b = ws + 58720256;
    unsigned short* w1b = w0b + 65536;
    unsigned short* wfb = w1b + 65536;

    dim3 blk(256);
    k_cvt<<<2048, blk, 0, stream>>>(input_1, A0, 2097152);
    k_cvtw<<<dim3(64, 3), blk, 0, stream>>>(w0, w1, wf, w0b, w1b, wfb);
    k_norm<<<8192, blk, 0, stream>>>(input_2, T);

    // adj = mask .* (T T^T)                      M=N=512/batch, K=256
    k_mfma<EPI_GRAM><<<dim3(4, 4, Bn), blk, 34816, stream>>>(
        T, T, adj, nullptr, noun, 256, 256, 256, (long)Nn * Dn, (long)Nn * Dn);
    // Ut0 = (input_1 @ w0^T)^T                   M=32768 flat, N=256, K=256
    k_mfma<EPI_TRANS><<<dim3(2, 256, 1), blk, 34816, stream>>>(
        A0, w0b, Ut, nullptr, nullptr, 256, 256, 256, 0, 0);
    // H1 = relu(adj @ Ut0^T + b0)                M=512/batch, N=256, K=512
    k_mfma<EPI_BIASH><<<dim3(2, 4, Bn), blk, 34816, stream>>>(
        adj, Ut, H1, b0, nullptr, 512, 512, 512, (long)Nn * Nn, (long)Dn * Nn);
    // Ut1 = (H1 @ w1^T)^T
    k_mfma<EPI_TRANS><<<dim3(2, 256, 1), blk, 34816, stream>>>(
        H1, w1b, Ut, nullptr, nullptr, 256, 256, 256, 0, 0);
    // H2 = relu(adj @ Ut1^T + b1)
    k_mfma<EPI_BIASH><<<dim3(2, 4, Bn), blk, 34816, stream>>>(
        adj, Ut, H2, b1, nullptr, 512, 512, 512, (long)Nn * Nn, (long)Dn * Nn);
    // out = relu(H2 @ wf^T + bf)  (fp32 out)
    k_mfma<EPI_FINAL><<<dim3(2, 256, 1), blk, 16384, stream>>>(
        H2, wfb, d_out, bf, nullptr, 256, 256, 256, 0, 0);
}

// Round 4
// 163.125 us; speedup vs baseline: 1.0175x; 1.0175x over previous
//
#include <hip/hip_runtime.h>
#include <math.h>

#define Bn   64
#define Nn   512
#define Dn   256
#define IMGn 51

typedef __attribute__((ext_vector_type(8))) short bf16x8;
typedef __attribute__((ext_vector_type(4))) float f32x4;
typedef __attribute__((ext_vector_type(4))) unsigned short u16x4;

__device__ inline unsigned short f2b(float f) {            // fp32 -> bf16 RNE
    union { float f; unsigned u; } v; v.f = f;
    unsigned r = v.u + 0x7fffu + ((v.u >> 16) & 1u);
    return (unsigned short)(r >> 16);
}

// ---------------- fp32 -> bf16 bulk convert (float4 / thread-iter) -------------
__global__ __launch_bounds__(256) void k_cvt(const float* __restrict__ in,
                                             unsigned short* __restrict__ out, int n4) {
    int stride = gridDim.x * 256;
    for (int i = blockIdx.x * 256 + threadIdx.x; i < n4; i += stride) {
        float4 v = ((const float4*)in)[i];
        u16x4 o = { f2b(v.x), f2b(v.y), f2b(v.z), f2b(v.w) };
        ((u16x4*)out)[i] = o;
    }
}

// three 256x256 weights in one launch (grid.y selects the pair)
__global__ __launch_bounds__(256) void k_cvtw(const float* __restrict__ w0,
                                              const float* __restrict__ w1,
                                              const float* __restrict__ wf,
                                              unsigned short* __restrict__ o0,
                                              unsigned short* __restrict__ o1,
                                              unsigned short* __restrict__ of) {
    const float* src = (blockIdx.y == 0) ? w0 : (blockIdx.y == 1) ? w1 : wf;
    unsigned short* dst = (blockIdx.y == 0) ? o0 : (blockIdx.y == 1) ? o1 : of;
    int i = blockIdx.x * 256 + threadIdx.x;
    float4 v = ((const float4*)src)[i];
    u16x4 o = { f2b(v.x), f2b(v.y), f2b(v.z), f2b(v.w) };
    ((u16x4*)dst)[i] = o;
}

// ---------------- row L2-normalize fp32 -> bf16, one wave per row --------------
__global__ __launch_bounds__(256) void k_norm(const float* __restrict__ in,
                                              unsigned short* __restrict__ out) {
    int idx  = blockIdx.x * 256 + threadIdx.x;
    int row  = idx >> 6;
    int lane = threadIdx.x & 63;
    float4 v = ((const float4*)(in + (size_t)row * Dn))[lane];
    float ss = v.x * v.x + v.y * v.y + v.z * v.z + v.w * v.w;
#pragma unroll
    for (int m = 1; m < 64; m <<= 1) ss += __shfl_xor(ss, m);
    float inv = 1.0f / fmaxf(sqrtf(ss), 1e-8f);
    u16x4 o = { f2b(v.x * inv), f2b(v.y * inv), f2b(v.z * inv), f2b(v.w * inv) };
    ((u16x4*)(out + (size_t)row * Dn))[lane] = o;
}

// ---------------- MFMA GEMM core: C = A(128xK) * Bt(128xK)^T -------------------
// Tile 128x128, BK=32, 4 waves (2x2), 4x4 frags of 16x16x32 per wave.
// 2-phase double-buffered staging: issue next K-tile's global_load_lds BEFORE
// ds_read+MFMA of current tile; __syncthreads() drain lands after compute.
// LDS: 4 x 8KB staging buffers (A0,B0,A1,B1); epilogue reuses smem as bounce.
// Source-side XOR swizzle (slot s of row r holds s ^ ((r>>1)&3)) keeps frag
// ds_read_b128 at free 2-way aliasing.

__device__ inline void stage128x32(const unsigned short* __restrict__ src, int ldk,
                                   char* ldsbase, int tid) {
    const int wave = tid >> 6, lane = tid & 63;
#pragma unroll
    for (int it = 0; it < 2; ++it) {
        const int chunk = wave * 128 + it * 64 + lane;   // 512 chunks of 16B
        const int row = chunk >> 2, s = chunk & 3;
        const char* g = (const char*)(src + (size_t)row * ldk) + ((s ^ ((row >> 1) & 3)) << 4);
        char* l = ldsbase + (size_t)(wave * 2048 + it * 1024);   // wave-uniform base
        __builtin_amdgcn_global_load_lds((const __attribute__((address_space(1))) void*)g,
                                         (__attribute__((address_space(3))) void*)l,
                                         16, 0, 0);
    }
}

__device__ inline bf16x8 frag(const char* ldsbase, int row, int s) {
    return *(const bf16x8*)(ldsbase + row * 64 + ((s ^ ((row >> 1) & 3)) << 4));
}

enum { EPI_GRAM = 0, EPI_TRANS = 1, EPI_BIASH = 2, EPI_FINAL = 3 };

template<int EPI>
__global__ __launch_bounds__(256) void k_mfma(const unsigned short* __restrict__ Abase,
                                              const unsigned short* __restrict__ Bbase,
                                              void* __restrict__ outp,
                                              const float* __restrict__ bias,
                                              const int* __restrict__ noun,
                                              int K, int lda, int ldb, long sA, long sB) {
    extern __shared__ char smem[];
    const int tid = threadIdx.x, lane = tid & 63, wave = tid >> 6;
    const int wr = wave >> 1, wc = wave & 1;
    const int r16 = lane & 15, s = lane >> 4;
    const size_t bz = blockIdx.z;
    const unsigned short* A  = Abase + bz * sA + (size_t)blockIdx.y * 128 * lda;
    const unsigned short* Bt = Bbase + bz * sB + (size_t)blockIdx.x * 128 * ldb;

    f32x4 acc[4][4];
#pragma unroll
    for (int m = 0; m < 4; ++m)
#pragma unroll
        for (int n = 0; n < 4; ++n)
            acc[m][n] = (f32x4){0.f, 0.f, 0.f, 0.f};

    // prologue: stage tile 0 into buffer 0
    stage128x32(A, lda, smem, tid);
    stage128x32(Bt, ldb, smem + 8192, tid);
    __syncthreads();

    int off = 0;
    for (int kt = 32; kt < K; kt += 32) {
        const int noff = off ^ 16384;
        // issue next tile's loads first (overlap with compute below)
        stage128x32(A + kt, lda, smem + noff, tid);
        stage128x32(Bt + kt, ldb, smem + 8192 + noff, tid);
        bf16x8 af[4], bv[4];
#pragma unroll
        for (int m = 0; m < 4; ++m) af[m] = frag(smem + off, wr * 64 + m * 16 + r16, s);
#pragma unroll
        for (int n = 0; n < 4; ++n) bv[n] = frag(smem + 8192 + off, wc * 64 + n * 16 + r16, s);
#pragma unroll
        for (int m = 0; m < 4; ++m)
#pragma unroll
            for (int n = 0; n < 4; ++n)
                acc[m][n] = __builtin_amdgcn_mfma_f32_16x16x32_bf16(af[m], bv[n], acc[m][n], 0, 0, 0);
        __syncthreads();   // drains next-tile vmcnt (after compute) + ds_read fence
        off = noff;
    }
    {   // final K-tile
        bf16x8 af[4], bv[4];
#pragma unroll
        for (int m = 0; m < 4; ++m) af[m] = frag(smem + off, wr * 64 + m * 16 + r16, s);
#pragma unroll
        for (int n = 0; n < 4; ++n) bv[n] = frag(smem + 8192 + off, wc * 64 + n * 16 + r16, s);
#pragma unroll
        for (int m = 0; m < 4; ++m)
#pragma unroll
            for (int n = 0; n < 4; ++n)
                acc[m][n] = __builtin_amdgcn_mfma_f32_16x16x32_bf16(af[m], bv[n], acc[m][n], 0, 0, 0);
    }
    __syncthreads();       // before reusing smem as epilogue bounce

    const int row0 = blockIdx.y * 128, col0 = blockIdx.x * 128;
    unsigned short* lt = (unsigned short*)smem;              // [128][136] bf16 bounce

    if constexpr (EPI == EPI_GRAM) {
        const int* nm = noun + bz * Nn;
#pragma unroll
        for (int n = 0; n < 4; ++n) {
            const int cl = wc * 64 + n * 16 + r16;
            const int c  = col0 + cl;
            const float nmc = (c < IMGn) ? 0.f : (float)nm[c];
#pragma unroll
            for (int m = 0; m < 4; ++m)
#pragma unroll
                for (int i = 0; i < 4; ++i) {
                    const int rl = wr * 64 + m * 16 + s * 4 + i;
                    const int r  = row0 + rl;
                    float mask;
                    if (r < IMGn)      mask = nmc;
                    else if (c < IMGn) mask = (float)nm[r];
                    else               mask = 1.f;
                    lt[rl * 136 + cl] = f2b(acc[m][n][i] * mask);
                }
        }
        __syncthreads();
        unsigned short* out = (unsigned short*)outp + bz * ((size_t)Nn * Nn);
        const int row = tid >> 1, h = tid & 1;
        const bf16x8* srcv = (const bf16x8*)(lt + (size_t)row * 136 + h * 64);
        bf16x8* dstv = (bf16x8*)(out + (size_t)(row0 + row) * Nn + col0 + h * 64);
#pragma unroll
        for (int q = 0; q < 8; ++q) dstv[q] = srcv[q];
    } else if constexpr (EPI == EPI_BIASH) {
#pragma unroll
        for (int n = 0; n < 4; ++n) {
            const int cl = wc * 64 + n * 16 + r16;
            const float bvv = bias[col0 + cl];
#pragma unroll
            for (int m = 0; m < 4; ++m)
#pragma unroll
                for (int i = 0; i < 4; ++i) {
                    const int rl = wr * 64 + m * 16 + s * 4 + i;
                    lt[rl * 136 + cl] = f2b(fmaxf(acc[m][n][i] + bvv, 0.f));
                }
        }
        __syncthreads();
        unsigned short* out = (unsigned short*)outp + bz * ((size_t)Nn * Dn);
        const int row = tid >> 1, h = tid & 1;
        const bf16x8* srcv = (const bf16x8*)(lt + (size_t)row * 136 + h * 64);
        bf16x8* dstv = (bf16x8*)(out + (size_t)(row0 + row) * Dn + col0 + h * 64);
#pragma unroll
        for (int q = 0; q < 8; ++q) dstv[q] = srcv[q];
    } else if constexpr (EPI == EPI_FINAL) {
        // fp32 out via LDS bounce, two 64-col passes; lt32 is [128][68] f32
        float* lt32 = (float*)smem;
        float* out = (float*)outp;
        const int row = tid >> 1, h = tid & 1;
#pragma unroll
        for (int p = 0; p < 2; ++p) {
            if (p) __syncthreads();
            if (wc == p) {
#pragma unroll
                for (int n = 0; n < 4; ++n) {
                    const int cll = n * 16 + r16;            // 0..63 within pass
                    const float bvv = bias[col0 + p * 64 + cll];
#pragma unroll
                    for (int m = 0; m < 4; ++m)
#pragma unroll
                        for (int i = 0; i < 4; ++i) {
                            const int rl = wr * 64 + m * 16 + s * 4 + i;
                            lt32[rl * 68 + cll] = fmaxf(acc[m][n][i] + bvv, 0.f);
                        }
                }
            }
            __syncthreads();
            const float4* srcv = (const float4*)(lt32 + (size_t)row * 68 + h * 32);
            float4* dstv = (float4*)(out + (size_t)(row0 + row) * Dn + col0 + p * 64 + h * 32);
#pragma unroll
            for (int q = 0; q < 8; ++q) dstv[q] = srcv[q];
        }
    } else {  // EPI_TRANS: out Ut[b][c][r_local], via padded-LDS transpose bounce
#pragma unroll
        for (int n = 0; n < 4; ++n)
#pragma unroll
            for (int m = 0; m < 4; ++m)
#pragma unroll
                for (int i = 0; i < 4; ++i) {
                    const int ct = wc * 64 + n * 16 + r16;
                    const int rt = wr * 64 + m * 16 + s * 4 + i;
                    lt[ct * 136 + rt] = f2b(acc[m][n][i]);
                }
        __syncthreads();
        const int bm = blockIdx.y;
        const size_t bb = bm >> 2;
        const int rl0 = (bm & 3) * 128;
        unsigned short* out = (unsigned short*)outp + bb * ((size_t)Dn * Nn);
        const int ct = tid >> 1, h = tid & 1;
        const bf16x8* srcv = (const bf16x8*)(lt + (size_t)ct * 136 + h * 64);
        bf16x8* dstv = (bf16x8*)(out + (size_t)(col0 + ct) * Nn + rl0 + h * 64);
#pragma unroll
        for (int q = 0; q < 8; ++q) dstv[q] = srcv[q];
    }
}

extern "C" void kernel_launch(void* const* d_in, const int* in_sizes, int n_in,
                              void* d_out, int out_size, void* d_ws, size_t ws_size,
                              hipStream_t stream) {
    const float* input_1 = (const float*)d_in[0];
    const float* input_2 = (const float*)d_in[1];
    const int*   noun    = (const int*)d_in[3];
    const float* w0 = (const float*)d_in[4];
    const float* b0 = (const float*)d_in[5];
    const float* w1 = (const float*)d_in[6];
    const float* b1 = (const float*)d_in[7];
    const float* wf = (const float*)d_in[8];
    const float* bf = (const float*)d_in[9];

    unsigned short* ws  = (unsigned short*)d_ws;
    unsigned short* T   = ws;                    // 64*512*256
    unsigned short* A0  = ws + 8388608;          // input_1 bf16
    unsigned short* adj = ws + 16777216;         // 64*512*512
    unsigned short* Ut  = ws + 33554432;         // 64*256*512
    unsigned short* H1  = ws + 41943040;
    unsigned short* H2  = ws + 50331648;
    unsigned short* w0b = ws + 58720256;
    unsigned short* w1b = w0b + 65536;
    unsigned short* wfb = w1b + 65536;

    dim3 blk(256);
    k_cvt<<<2048, blk, 0, stream>>>(input_1, A0, 2097152);
    k_cvtw<<<dim3(64, 3), blk, 0, stream>>>(w0, w1, wf, w0b, w1b, wfb);
    k_norm<<<8192, blk, 0, stream>>>(input_2, T);

    // adj = mask .* (T T^T)                      M=N=512/batch, K=256
    k_mfma<EPI_GRAM><<<dim3(4, 4, Bn), blk, 34816, stream>>>(
        T, T, adj, nullptr, noun, 256, 256, 256, (long)Nn * Dn, (long)Nn * Dn);
    // Ut0 = (input_1 @ w0^T)^T                   M=32768 flat, N=256, K=256
    k_mfma<EPI_TRANS><<<dim3(2, 256, 1), blk, 34816, stream>>>(
        A0, w0b, Ut, nullptr, nullptr, 256, 256, 256, 0, 0);
    // H1 = relu(adj @ Ut0^T + b0)                M=512/batch, N=256, K=512
    k_mfma<EPI_BIASH><<<dim3(2, 4, Bn), blk, 34816, stream>>>(
        adj, Ut, H1, b0, nullptr, 512, 512, 512, (long)Nn * Nn, (long)Dn * Nn);
    // Ut1 = (H1 @ w1^T)^T
    k_mfma<EPI_TRANS><<<dim3(2, 256, 1), blk, 34816, stream>>>(
        H1, w1b, Ut, nullptr, nullptr, 256, 256, 256, 0, 0);
    // H2 = relu(adj @ Ut1^T + b1)
    k_mfma<EPI_BIASH><<<dim3(2, 4, Bn), blk, 34816, stream>>>(
        adj, Ut, H2, b1, nullptr, 512, 512, 512, (long)Nn * Nn, (long)Dn * Nn);
    // out = relu(H2 @ wf^T + bf)  (fp32 out)
    k_mfma<EPI_FINAL><<<dim3(2, 256, 1), blk, 34816, stream>>>(
        H2, wfb, d_out, bf, nullptr, 256, 256, 256, 0, 0);
}

// Round 5
// 139.803 us; speedup vs baseline: 1.1873x; 1.1668x over previous
//
#include <hip/hip_runtime.h>
#include <math.h>

#define Bn   64
#define Nn   512
#define Dn   256
#define IMGn 51

typedef __attribute__((ext_vector_type(8))) short bf16x8;
typedef __attribute__((ext_vector_type(4))) float f32x4;
typedef __attribute__((ext_vector_type(4))) unsigned short u16x4;

__device__ inline unsigned short f2b(float f) {            // fp32 -> bf16 RNE
    union { float f; unsigned u; } v; v.f = f;
    unsigned r = v.u + 0x7fffu + ((v.u >> 16) & 1u);
    return (unsigned short)(r >> 16);
}

// ---- fused prep: l2norm(input_2)->T, cvt(input_1)->A0, cvt weights ------------
__global__ __launch_bounds__(256) void k_prep(const float* __restrict__ in1,
                                              const float* __restrict__ in2,
                                              const float* __restrict__ w0,
                                              const float* __restrict__ w1,
                                              const float* __restrict__ wf,
                                              unsigned short* __restrict__ A0,
                                              unsigned short* __restrict__ T,
                                              unsigned short* __restrict__ w0b,
                                              unsigned short* __restrict__ w1b,
                                              unsigned short* __restrict__ wfb) {
    const int bid = blockIdx.x, tid = threadIdx.x;
    if (bid < 8192) {                                      // norm: 4 rows/block
        const int row = bid * 4 + (tid >> 6);
        const int lane = tid & 63;
        float4 v = ((const float4*)(in2 + (size_t)row * Dn))[lane];
        float ss = v.x * v.x + v.y * v.y + v.z * v.z + v.w * v.w;
#pragma unroll
        for (int m = 1; m < 64; m <<= 1) ss += __shfl_xor(ss, m);
        float inv = 1.0f / fmaxf(sqrtf(ss), 1e-8f);
        u16x4 o = { f2b(v.x*inv), f2b(v.y*inv), f2b(v.z*inv), f2b(v.w*inv) };
        ((u16x4*)(T + (size_t)row * Dn))[lane] = o;
    } else if (bid < 10240) {                              // cvt input_1
        int i = (bid - 8192) * 256 + tid;
#pragma unroll
        for (int q = 0; q < 4; ++q, i += 524288) {
            float4 v = ((const float4*)in1)[i];
            u16x4 o = { f2b(v.x), f2b(v.y), f2b(v.z), f2b(v.w) };
            ((u16x4*)A0)[i] = o;
        }
    } else {                                               // cvt weights
        const int b2 = bid - 10240;
        const float* src = (b2 < 64) ? w0 : (b2 < 128) ? w1 : wf;
        unsigned short* dst = (b2 < 64) ? w0b : (b2 < 128) ? w1b : wfb;
        const int i = (b2 & 63) * 256 + tid;
        float4 v = ((const float4*)src)[i];
        u16x4 o = { f2b(v.x), f2b(v.y), f2b(v.z), f2b(v.w) };
        ((u16x4*)dst)[i] = o;
    }
}

// ---------------- MFMA GEMM core: C = A(128xK) * Bt(128xK)^T -------------------
// Tile 128x128, BK=32, 4 waves (2x2), 4x4 frags of 16x16x32 per wave.
// 3-buffer staging with COUNTED vmcnt (never drains to 0 in-loop): tile t's
// loads are issued 2 iterations ahead; one raw s_barrier per iteration.
// Source-side XOR swizzle keeps frag ds_read_b128 at free 2-way aliasing.

__device__ inline void stage128x32(const unsigned short* __restrict__ src, int ldk,
                                   char* ldsbase, int tid) {
    const int wave = tid >> 6, lane = tid & 63;
#pragma unroll
    for (int it = 0; it < 2; ++it) {
        const int chunk = wave * 128 + it * 64 + lane;   // 512 chunks of 16B
        const int row = chunk >> 2, s = chunk & 3;
        const char* g = (const char*)(src + (size_t)row * ldk) + ((s ^ ((row >> 1) & 3)) << 4);
        char* l = ldsbase + (size_t)(wave * 2048 + it * 1024);   // wave-uniform base
        __builtin_amdgcn_global_load_lds((const __attribute__((address_space(1))) void*)g,
                                         (__attribute__((address_space(3))) void*)l,
                                         16, 0, 0);
    }
}

__device__ inline bf16x8 frag(const char* ldsbase, int row, int s) {
    return *(const bf16x8*)(ldsbase + row * 64 + ((s ^ ((row >> 1) & 3)) << 4));
}

enum { EPI_GRAM = 0, EPI_TRANS = 1, EPI_BIASH = 2, EPI_FINAL = 3 };

template<int EPI>
__global__ __launch_bounds__(256) void k_mfma(const unsigned short* __restrict__ Abase,
                                              const unsigned short* __restrict__ Bbase,
                                              void* __restrict__ outp,
                                              const float* __restrict__ bias,
                                              const int* __restrict__ noun,
                                              int K, int lda, int ldb, long sA, long sB) {
    extern __shared__ char smem[];
    const int tid = threadIdx.x, lane = tid & 63, wave = tid >> 6;
    const int wr = wave >> 1, wc = wave & 1;
    const int r16 = lane & 15, s = lane >> 4;

    // bijective XCD swizzle (all our grids have nwg % 8 == 0)
    const int nwg = gridDim.x * gridDim.y * gridDim.z;
    const int wg  = blockIdx.x + gridDim.x * (blockIdx.y + gridDim.y * blockIdx.z);
    const int swz = (wg & 7) * (nwg >> 3) + (wg >> 3);
    const int bx  = swz % gridDim.x;
    const int rem = swz / gridDim.x;
    const int by  = rem % gridDim.y;
    const size_t bz = rem / gridDim.y;

    int tile_y, tile_x;
    if constexpr (EPI == EPI_GRAM) {                       // upper-tri tile map
        if (bx < 4)      { tile_y = 0; tile_x = bx; }
        else if (bx < 7) { tile_y = 1; tile_x = bx - 3; }
        else if (bx < 9) { tile_y = 2; tile_x = bx - 5; }
        else             { tile_y = 3; tile_x = 3; }
    } else { tile_y = by; tile_x = bx; }

    const unsigned short* A  = Abase + bz * sA + (size_t)tile_y * 128 * lda;
    const unsigned short* Bt = Bbase + bz * sB + (size_t)tile_x * 128 * ldb;

    f32x4 acc[4][4];
#pragma unroll
    for (int m = 0; m < 4; ++m)
#pragma unroll
        for (int n = 0; n < 4; ++n)
            acc[m][n] = (f32x4){0.f, 0.f, 0.f, 0.f};

    const int NT = K >> 5;
    // prologue: 2 tiles in flight
    stage128x32(A,      lda, smem,         tid);
    stage128x32(Bt,     ldb, smem + 8192,  tid);
    stage128x32(A + 32, lda, smem + 16384, tid);
    stage128x32(Bt + 32, ldb, smem + 16384 + 8192, tid);

    for (int t = 0; t < NT; ++t) {
        if (t < NT - 1) { asm volatile("s_waitcnt vmcnt(4)" ::: "memory"); }
        else            { asm volatile("s_waitcnt vmcnt(0)" ::: "memory"); }
        __builtin_amdgcn_s_barrier();
        __builtin_amdgcn_sched_barrier(0);
        if (t + 2 < NT) {                                  // issue tile t+2
            char* nb = smem + 16384 * ((t + 2) % 3);
            stage128x32(A  + (t + 2) * 32, lda, nb,        tid);
            stage128x32(Bt + (t + 2) * 32, ldb, nb + 8192, tid);
        }
        __builtin_amdgcn_sched_barrier(0);
        const char* cb = smem + 16384 * (t % 3);
        bf16x8 af[4], bv[4];
#pragma unroll
        for (int m = 0; m < 4; ++m) af[m] = frag(cb, wr * 64 + m * 16 + r16, s);
#pragma unroll
        for (int n = 0; n < 4; ++n) bv[n] = frag(cb + 8192, wc * 64 + n * 16 + r16, s);
#pragma unroll
        for (int m = 0; m < 4; ++m)
#pragma unroll
            for (int n = 0; n < 4; ++n)
                acc[m][n] = __builtin_amdgcn_mfma_f32_16x16x32_bf16(af[m], bv[n], acc[m][n], 0, 0, 0);
    }
    __syncthreads();       // before reusing smem as epilogue bounce

    const int row0 = tile_y * 128, col0 = tile_x * 128;
    unsigned short* lt = (unsigned short*)smem;            // [128][136] bf16 bounce
    const int row = tid >> 1, h = tid & 1;

    if constexpr (EPI == EPI_GRAM) {
        const int* nm = noun + bz * Nn;
        unsigned short* out = (unsigned short*)outp + bz * ((size_t)Nn * Nn);
#pragma unroll
        for (int n = 0; n < 4; ++n) {
            const int cl = wc * 64 + n * 16 + r16;
            const int c  = col0 + cl;
            const float nmc = (c < IMGn) ? 0.f : (float)nm[c];
#pragma unroll
            for (int m = 0; m < 4; ++m)
#pragma unroll
                for (int i = 0; i < 4; ++i) {
                    const int rl = wr * 64 + m * 16 + s * 4 + i;
                    const int r  = row0 + rl;
                    float mask;
                    if (r < IMGn)      mask = nmc;
                    else if (c < IMGn) mask = (float)nm[r];
                    else               mask = 1.f;
                    lt[rl * 136 + cl] = f2b(acc[m][n][i] * mask);
                }
        }
        __syncthreads();
        {
            const bf16x8* srcv = (const bf16x8*)(lt + (size_t)row * 136 + h * 64);
            bf16x8* dstv = (bf16x8*)(out + (size_t)(row0 + row) * Nn + col0 + h * 64);
#pragma unroll
            for (int q = 0; q < 8; ++q) dstv[q] = srcv[q];
        }
        if (tile_x != tile_y) {                            // mirror tile (adj symmetric)
            __syncthreads();
#pragma unroll
            for (int n = 0; n < 4; ++n) {
                const int cl = wc * 64 + n * 16 + r16;
                const int c  = col0 + cl;
                const float nmc = (c < IMGn) ? 0.f : (float)nm[c];
#pragma unroll
                for (int m = 0; m < 4; ++m)
#pragma unroll
                    for (int i = 0; i < 4; ++i) {
                        const int rl = wr * 64 + m * 16 + s * 4 + i;
                        const int r  = row0 + rl;
                        float mask;
                        if (r < IMGn)      mask = nmc;
                        else if (c < IMGn) mask = (float)nm[r];
                        else               mask = 1.f;
                        lt[cl * 136 + rl] = f2b(acc[m][n][i] * mask);
                    }
            }
            __syncthreads();
            const bf16x8* srcv = (const bf16x8*)(lt + (size_t)row * 136 + h * 64);
            bf16x8* dstv = (bf16x8*)(out + (size_t)(col0 + row) * Nn + row0 + h * 64);
#pragma unroll
            for (int q = 0; q < 8; ++q) dstv[q] = srcv[q];
        }
    } else if constexpr (EPI == EPI_BIASH) {
#pragma unroll
        for (int n = 0; n < 4; ++n) {
            const int cl = wc * 64 + n * 16 + r16;
            const float bvv = bias[col0 + cl];
#pragma unroll
            for (int m = 0; m < 4; ++m)
#pragma unroll
                for (int i = 0; i < 4; ++i) {
                    const int rl = wr * 64 + m * 16 + s * 4 + i;
                    lt[rl * 136 + cl] = f2b(fmaxf(acc[m][n][i] + bvv, 0.f));
                }
        }
        __syncthreads();
        unsigned short* out = (unsigned short*)outp + bz * ((size_t)Nn * Dn);
        const bf16x8* srcv = (const bf16x8*)(lt + (size_t)row * 136 + h * 64);
        bf16x8* dstv = (bf16x8*)(out + (size_t)(row0 + row) * Dn + col0 + h * 64);
#pragma unroll
        for (int q = 0; q < 8; ++q) dstv[q] = srcv[q];
    } else if constexpr (EPI == EPI_FINAL) {
        // fp32 out via LDS bounce, two 64-col passes; lt32 is [128][68] f32
        float* lt32 = (float*)smem;
        float* out = (float*)outp;
#pragma unroll
        for (int p = 0; p < 2; ++p) {
            if (p) __syncthreads();
            if (wc == p) {
#pragma unroll
                for (int n = 0; n < 4; ++n) {
                    const int cll = n * 16 + r16;
                    const float bvv = bias[col0 + p * 64 + cll];
#pragma unroll
                    for (int m = 0; m < 4; ++m)
#pragma unroll
                        for (int i = 0; i < 4; ++i) {
                            const int rl = wr * 64 + m * 16 + s * 4 + i;
                            lt32[rl * 68 + cll] = fmaxf(acc[m][n][i] + bvv, 0.f);
                        }
                }
            }
            __syncthreads();
            const float4* srcv = (const float4*)(lt32 + (size_t)row * 68 + h * 32);
            float4* dstv = (float4*)(out + (size_t)(row0 + row) * Dn + col0 + p * 64 + h * 32);
#pragma unroll
            for (int q = 0; q < 8; ++q) dstv[q] = srcv[q];
        }
    } else {  // EPI_TRANS: out Ut[b][c][r_local], via padded-LDS transpose bounce
#pragma unroll
        for (int n = 0; n < 4; ++n)
#pragma unroll
            for (int m = 0; m < 4; ++m)
#pragma unroll
                for (int i = 0; i < 4; ++i) {
                    const int ct = wc * 64 + n * 16 + r16;
                    const int rt = wr * 64 + m * 16 + s * 4 + i;
                    lt[ct * 136 + rt] = f2b(acc[m][n][i]);
                }
        __syncthreads();
        const int bm = tile_y;
        const size_t bb = bm >> 2;
        const int rl0 = (bm & 3) * 128;
        unsigned short* out = (unsigned short*)outp + bb * ((size_t)Dn * Nn);
        const int ct = tid >> 1;
        const bf16x8* srcv = (const bf16x8*)(lt + (size_t)ct * 136 + h * 64);
        bf16x8* dstv = (bf16x8*)(out + (size_t)(col0 + ct) * Nn + rl0 + h * 64);
#pragma unroll
        for (int q = 0; q < 8; ++q) dstv[q] = srcv[q];
    }
}

extern "C" void kernel_launch(void* const* d_in, const int* in_sizes, int n_in,
                              void* d_out, int out_size, void* d_ws, size_t ws_size,
                              hipStream_t stream) {
    const float* input_1 = (const float*)d_in[0];
    const float* input_2 = (const float*)d_in[1];
    const int*   noun    = (const int*)d_in[3];
    const float* w0 = (const float*)d_in[4];
    const float* b0 = (const float*)d_in[5];
    const float* w1 = (const float*)d_in[6];
    const float* b1 = (const float*)d_in[7];
    const float* wf = (const float*)d_in[8];
    const float* bf = (const float*)d_in[9];

    unsigned short* ws  = (unsigned short*)d_ws;
    unsigned short* T   = ws;                    // 64*512*256
    unsigned short* A0  = ws + 8388608;          // input_1 bf16
    unsigned short* adj = ws + 16777216;         // 64*512*512
    unsigned short* Ut  = ws + 33554432;         // 64*256*512
    unsigned short* H1  = ws + 41943040;
    unsigned short* H2  = ws + 50331648;
    unsigned short* w0b = ws + 58720256;
    unsigned short* w1b = w0b + 65536;
    unsigned short* wfb = w1b + 65536;

    dim3 blk(256);
    k_prep<<<10432, blk, 0, stream>>>(input_1, input_2, w0, w1, wf, A0, T, w0b, w1b, wfb);

    // adj = mask .* (T T^T), symmetric: 10 upper tiles, mirror-stored
    k_mfma<EPI_GRAM><<<dim3(10, 1, Bn), blk, 49152, stream>>>(
        T, T, adj, nullptr, noun, 256, 256, 256, (long)Nn * Dn, (long)Nn * Dn);
    // Ut0 = (input_1 @ w0^T)^T                   M=32768 flat, N=256, K=256
    k_mfma<EPI_TRANS><<<dim3(2, 256, 1), blk, 49152, stream>>>(
        A0, w0b, Ut, nullptr, nullptr, 256, 256, 256, 0, 0);
    // H1 = relu(adj @ Ut0^T + b0)                M=512/batch, N=256, K=512
    k_mfma<EPI_BIASH><<<dim3(2, 4, Bn), blk, 49152, stream>>>(
        adj, Ut, H1, b0, nullptr, 512, 512, 512, (long)Nn * Nn, (long)Dn * Nn);
    // Ut1 = (H1 @ w1^T)^T
    k_mfma<EPI_TRANS><<<dim3(2, 256, 1), blk, 49152, stream>>>(
        H1, w1b, Ut, nullptr, nullptr, 256, 256, 256, 0, 0);
    // H2 = relu(adj @ Ut1^T + b1)
    k_mfma<EPI_BIASH><<<dim3(2, 4, Bn), blk, 49152, stream>>>(
        adj, Ut, H2, b1, nullptr, 512, 512, 512, (long)Nn * Nn, (long)Dn * Nn);
    // out = relu(H2 @ wf^T + bf)  (fp32 out)
    k_mfma<EPI_FINAL><<<dim3(2, 256, 1), blk, 49152, stream>>>(
        H2, wfb, d_out, bf, nullptr, 256, 256, 256, 0, 0);
}